// Round 18
// baseline (44.340 us; speedup 1.0000x reference)
//
#include <hip/hip_runtime.h>

#define THREADS 256
#define NB 4                 // batches
#define NPTS 8192            // points per cloud
#define CHT 32               // A-tiles per LDS chunk (32 KB)
#define NCH 8                // target chunks per (dir,b)
#define FXSCALE 1048576.0f   // 2^20 fixed-point for deterministic atomic sum

typedef __attribute__((ext_vector_type(8))) short short8;   // 8 bf16 = 4 VGPR
typedef __attribute__((ext_vector_type(16))) float f32x16;  // MFMA 32x32 acc

__device__ inline unsigned short f2b(float f) {  // f32 -> bf16 RNE (no NaN inputs here)
    unsigned u = __float_as_uint(f);
    return (unsigned short)((u + 0x7FFFu + ((u >> 16) & 1u)) >> 16);
}
__device__ inline float b2f(unsigned short h) {
    return __uint_as_float(((unsigned)h) << 16);
}

// Fragment K-slot plan (verified absmax=0 rounds 7-17):
// A (targets, rows; lane row=l&31, kgrp=l>>5):
//   kgrp0: [ghx ghy ghz glx gly glz ghx ghy]  kgrp1: [ghz g2h g2l 0 0 0 0 0]
// B (queries, cols; a=split(-2p)):
//   kgrp0: [ahx ahy ahz ahx ahy ahz alx aly]  kgrp1: [alz 1 1 0 0 0 0 0]
// => acc[target][query] = |g|^2 - 2 p.g  (+|p|^2 in epilogue)

// r13-proven form: VGPR-dest MFMA pair, C = inline 0, 18 wait states before
// any external VALU read (hazard recognizer can't see into asm).
#define MFMA_PAIR(c0, c1, a0, a1, bq)                                      \
    asm("v_mfma_f32_32x32x16_bf16 %0, %2, %4, 0\n\t"                       \
        "v_mfma_f32_32x32x16_bf16 %1, %3, %4, 0\n\t"                       \
        "s_nop 7\n\t"                                                      \
        "s_nop 7\n\t"                                                      \
        "s_nop 1"                                                          \
        : "=&v"(c0), "=&v"(c1)                                             \
        : "v"(a0), "v"(a1), "v"(bq))

// Folded consumption: 16 min3 into vm[4] (r17-proven, saves 12 regs/query)
#define CONSUME(vm, c0, c1)                                                \
    _Pragma("unroll")                                                      \
    for (int i = 0; i < 4; ++i) {                                          \
        vm[i] = fminf(vm[i], fminf(c0[i], c0[i + 4]));                     \
        vm[i] = fminf(vm[i], fminf(c0[i + 8], c0[i + 12]));                \
        vm[i] = fminf(vm[i], fminf(c1[i], c1[i + 4]));                     \
        vm[i] = fminf(vm[i], fminf(c1[i + 8], c1[i + 12]));                \
    }

// Build one query tile's B-fragment + |p|^2
#define BUILD_BQ(bq, p2v, qj)                                              \
    {                                                                      \
        float px = q[qj], py = q[N + qj], pz = q[2 * N + qj];              \
        p2v = fmaf(px, px, fmaf(py, py, pz * pz));                         \
        float ax = -2.f * px, ay = -2.f * py, az = -2.f * pz;              \
        unsigned short ahx = f2b(ax), ahy = f2b(ay), ahz = f2b(az);        \
        unsigned short alx = f2b(ax - b2f(ahx)), aly = f2b(ay - b2f(ahy)), \
                       alz = f2b(az - b2f(ahz));                           \
        short8 v0, v1;                                                     \
        v0[0]=(short)ahx; v0[1]=(short)ahy; v0[2]=(short)ahz;              \
        v0[3]=(short)ahx; v0[4]=(short)ahy; v0[5]=(short)ahz;              \
        v0[6]=(short)alx; v0[7]=(short)aly;                                \
        v1[0]=(short)alz; v1[1]=ONE; v1[2]=ONE; v1[3]=0;                   \
        v1[4]=0; v1[5]=0; v1[6]=0; v1[7]=0;                                \
        bq = hi ? v1 : v0;                                                 \
    }

// Fused: stage A-chunk fragments in LDS from raw coords; 4 query tiles/wave.
// block = (dir, b, chunk, qg); 1024 blocks (half of r13 -> half prologue tax,
// 2x MFMA per ds_read). Block 0 re-zeroes the reduction accumulator.
__global__ __launch_bounds__(THREADS, 4) void nn_fused_kernel(
    const float* __restrict__ pred, const float* __restrict__ gt,
    float* __restrict__ pmin, unsigned long long* __restrict__ facc, int N)
{
    __shared__ short8 lA[CHT * 64];   // 32 KB

    int wave = threadIdx.x >> 6;
    int lane = threadIdx.x & 63;
    int blk = blockIdx.x;             // [0, 1024)
    if (blk == 0 && threadIdx.x == 0) { facc[0] = 0ull; facc[1] = 0ull; }
    int dir   = blk >> 9;
    int b     = (blk >> 7) & 3;
    int chunk = (blk >> 4) & 7;       // 8 chunks of 32 tiles (1024 targets)
    int qg    = blk & 15;             // 16 query groups (x4 waves x4 tiles)

    const float* q = (dir ? gt : pred) + (size_t)b * 3 * N;  // queries
    const float* t = (dir ? pred : gt) + (size_t)b * 3 * N;  // targets

    // ---- stage A-chunk: 1024 targets, 4 per thread, coalesced in jj ----
    int cbase = chunk * (CHT * 32);
    #pragma unroll
    for (int k = 0; k < 4; ++k) {
        int jj = k * THREADS + threadIdx.x;      // [0,1024)
        int j  = cbase + jj;
        float gx = t[j], gy = t[N + j], gz = t[2 * N + j];
        unsigned short ghx = f2b(gx), ghy = f2b(gy), ghz = f2b(gz);
        unsigned short glx = f2b(gx - b2f(ghx)), gly = f2b(gy - b2f(ghy)), glz = f2b(gz - b2f(ghz));
        float g2 = fmaf(gx, gx, fmaf(gy, gy, gz * gz));
        unsigned short g2h = f2b(g2), g2l = f2b(g2 - b2f(g2h));
        short8 ta0, ta1;
        ta0[0]=(short)ghx; ta0[1]=(short)ghy; ta0[2]=(short)ghz; ta0[3]=(short)glx;
        ta0[4]=(short)gly; ta0[5]=(short)glz; ta0[6]=(short)ghx; ta0[7]=(short)ghy;
        ta1[0]=(short)ghz; ta1[1]=(short)g2h; ta1[2]=(short)g2l; ta1[3]=0;
        ta1[4]=0; ta1[5]=0; ta1[6]=0; ta1[7]=0;
        int tile = jj >> 5, c = jj & 31;
        lA[tile * 64 + c]      = ta0;
        lA[tile * 64 + 32 + c] = ta1;
    }

    // ---- build this wave's 4 B-fragments + |p|^2 ----
    int qt = qg * 16 + wave * 4;             // first query tile [0,256)
    int hi = lane >> 5;
    int col = lane & 31;
    const short ONE = (short)0x3F80;

    short8 bq0, bq1, bq2, bq3;
    float p20, p21, p22, p23;
    BUILD_BQ(bq0, p20, (qt + 0) * 32 + col);
    BUILD_BQ(bq1, p21, (qt + 1) * 32 + col);
    BUILD_BQ(bq2, p22, (qt + 2) * 32 + col);
    BUILD_BQ(bq3, p23, (qt + 3) * 32 + col);

    float vm0[4], vm1[4], vm2[4], vm3[4];
    #pragma unroll
    for (int i = 0; i < 4; ++i) {
        vm0[i] = 3.0e38f; vm1[i] = 3.0e38f; vm2[i] = 3.0e38f; vm3[i] = 3.0e38f;
    }

    __syncthreads();

    // ---- main loop: per tile-pair, 8 MFMAs + 64 min3 (2x r13 intensity) ----
    #pragma unroll 2
    for (int tt = 0; tt < CHT; tt += 2) {
        short8 a0 = lA[tt * 64 + lane];
        short8 a1 = lA[tt * 64 + 64 + lane];
        {
            f32x16 c0, c1;
            MFMA_PAIR(c0, c1, a0, a1, bq0);
            CONSUME(vm0, c0, c1);
        }
        {
            f32x16 c0, c1;
            MFMA_PAIR(c0, c1, a0, a1, bq1);
            CONSUME(vm1, c0, c1);
        }
        {
            f32x16 c0, c1;
            MFMA_PAIR(c0, c1, a0, a1, bq2);
            CONSUME(vm2, c0, c1);
        }
        {
            f32x16 c0, c1;
            MFMA_PAIR(c0, c1, a0, a1, bq3);
            CONSUME(vm3, c0, c1);
        }
    }

    // ---- epilogue: horizontal min + xor-32 merge + partial store ----
    int qbase = (dir * NB + b) * N;
    #pragma unroll
    for (int qi = 0; qi < 4; ++qi) {
        const float* vv = qi == 0 ? vm0 : qi == 1 ? vm1 : qi == 2 ? vm2 : vm3;
        float p2 = qi == 0 ? p20 : qi == 1 ? p21 : qi == 2 ? p22 : p23;
        float v = fminf(fminf(vv[0], vv[1]), fminf(vv[2], vv[3]));
        v = fminf(v, __shfl_xor(v, 32));
        if (lane < 32) {
            int gi = qbase + (qt + qi) * 32 + lane;
            pmin[(size_t)gi * NCH + chunk] = fmaxf(v + p2, 0.f);
        }
    }
}

// reduce1 + fused finish: 8-way chunk min + sqrt + block sum, then u64
// fixed-point atomic accumulate (exact/deterministic); last block writes out.
__global__ __launch_bounds__(THREADS) void reduce1_pmin_kernel(
    const float* __restrict__ pmin, unsigned long long* __restrict__ facc,
    float* __restrict__ out, int totalQ, float inv)
{
    __shared__ float sdata[THREADS];
    float s = 0.f;
    for (int gi = blockIdx.x * THREADS + threadIdx.x; gi < totalQ; gi += gridDim.x * THREADS) {
        const float4* p = (const float4*)(pmin + (size_t)gi * NCH);
        float4 u = p[0], w = p[1];
        float m = fminf(fminf(fminf(u.x, u.y), fminf(u.z, u.w)),
                        fminf(fminf(w.x, w.y), fminf(w.z, w.w)));
        s += sqrtf(m + 1e-8f);
    }
    sdata[threadIdx.x] = s;
    __syncthreads();
    for (int off = THREADS / 2; off > 0; off >>= 1) {
        if (threadIdx.x < off) sdata[threadIdx.x] += sdata[threadIdx.x + off];
        __syncthreads();
    }
    if (threadIdx.x == 0) {
        unsigned long long fx = (unsigned long long)((double)sdata[0] * FXSCALE + 0.5);
        atomicAdd(&facc[0], fx);
        __threadfence();
        unsigned long long done = atomicAdd(&facc[1], 1ull);
        if (done == (unsigned long long)(gridDim.x - 1)) {
            unsigned long long total = atomicAdd(&facc[0], 0ull);
            out[0] = (float)((double)total * (double)inv / (double)FXSCALE);
        }
    }
}

// Fallback (unexpected shape): direct f32 path + atomicMin on uint bits.
__global__ __launch_bounds__(THREADS) void nn_fallback_kernel(
    const float* __restrict__ pred, const float* __restrict__ gt,
    unsigned int* __restrict__ minsq, int N, int B, int nQC, int nTC, int blocksPerDir)
{
    int blk = blockIdx.x;
    int dir = blk / blocksPerDir;
    blk -= dir * blocksPerDir;
    int tc = blk % nTC;
    int qc = (blk / nTC) % nQC;
    int b  = blk / (nTC * nQC);
    const float* q = (dir ? gt : pred) + (size_t)b * 3 * N;
    const float* t = (dir ? pred : gt) + (size_t)b * 3 * N + tc * 256;
    float px[4], py[4], pz[4], p2[4], mn[4];
    int q0 = qc * 1024 + threadIdx.x;
    #pragma unroll
    for (int r = 0; r < 4; ++r) {
        int qi = q0 + r * THREADS;
        px[r] = -2.f * q[qi]; py[r] = -2.f * q[N + qi]; pz[r] = -2.f * q[2 * N + qi];
        p2[r] = fmaf(q[qi], q[qi], fmaf(q[N + qi], q[N + qi], q[2 * N + qi] * q[2 * N + qi]));
        mn[r] = 3.0e38f;
    }
    for (int j = 0; j < 256; j += 4) {
        float4 gx4 = *(const float4*)&t[j];
        float4 gy4 = *(const float4*)&t[N + j];
        float4 gz4 = *(const float4*)&t[2 * N + j];
        float g2_0 = fmaf(gx4.x, gx4.x, fmaf(gy4.x, gy4.x, gz4.x * gz4.x));
        float g2_1 = fmaf(gx4.y, gx4.y, fmaf(gy4.y, gy4.y, gz4.y * gz4.y));
        float g2_2 = fmaf(gx4.z, gx4.z, fmaf(gy4.z, gy4.z, gz4.z * gz4.z));
        float g2_3 = fmaf(gx4.w, gx4.w, fmaf(gy4.w, gy4.w, gz4.w * gz4.w));
        #pragma unroll
        for (int r = 0; r < 4; ++r) {
            float d0 = fmaf(gx4.x, px[r], fmaf(gy4.x, py[r], fmaf(gz4.x, pz[r], g2_0)));
            float d1 = fmaf(gx4.y, px[r], fmaf(gy4.y, py[r], fmaf(gz4.y, pz[r], g2_1)));
            float d2 = fmaf(gx4.z, px[r], fmaf(gy4.z, py[r], fmaf(gz4.z, pz[r], g2_2)));
            float d3 = fmaf(gx4.w, px[r], fmaf(gy4.w, py[r], fmaf(gz4.w, pz[r], g2_3)));
            mn[r] = fminf(fminf(d0, d1), mn[r]);
            mn[r] = fminf(fminf(d2, d3), mn[r]);
        }
    }
    unsigned int* mb = minsq + ((size_t)dir * B + b) * N;
    #pragma unroll
    for (int r = 0; r < 4; ++r) {
        float d2 = fmaxf(mn[r] + p2[r], 0.f);
        atomicMin(&mb[q0 + r * THREADS], __float_as_uint(d2));
    }
}

__global__ __launch_bounds__(THREADS) void reduce1_direct_kernel(
    const unsigned int* __restrict__ minsq, float* __restrict__ partials, int total)
{
    __shared__ float sdata[THREADS];
    float s = 0.f;
    for (int i = blockIdx.x * THREADS + threadIdx.x; i < total; i += gridDim.x * THREADS) {
        float v = __uint_as_float(minsq[i]);
        s += sqrtf(v + 1e-8f);
    }
    sdata[threadIdx.x] = s;
    __syncthreads();
    for (int off = THREADS / 2; off > 0; off >>= 1) {
        if (threadIdx.x < off) sdata[threadIdx.x] += sdata[threadIdx.x + off];
        __syncthreads();
    }
    if (threadIdx.x == 0) partials[blockIdx.x] = sdata[0];
}

__global__ __launch_bounds__(64) void reduce2_kernel(
    const float* __restrict__ partials, float* __restrict__ out, float inv)
{
    float s = partials[threadIdx.x];
    #pragma unroll
    for (int off = 32; off > 0; off >>= 1) s += __shfl_down(s, off);
    if (threadIdx.x == 0) out[0] = s * inv;
}

extern "C" void kernel_launch(void* const* d_in, const int* in_sizes, int n_in,
                              void* d_out, int out_size, void* d_ws, size_t ws_size,
                              hipStream_t stream) {
    const float* pred = (const float*)d_in[0];
    const float* gt   = (const float*)d_in[1];
    const int N = 8192;
    const int B = in_sizes[0] / (3 * N);
    int totalQ = 2 * B * N;                               // 65536

    float* pmin = (float*)d_ws;                           // 2*B*N*8 floats = 2 MB
    unsigned long long* facc = (unsigned long long*)((char*)d_ws + (4 << 20)); // acc,cnt
    float* partials = (float*)((char*)d_ws + (4 << 20) + 256);                 // fallback

    if (B == NB && N == NPTS) {
        nn_fused_kernel<<<1024, THREADS, 0, stream>>>(pred, gt, pmin, facc, N);
        reduce1_pmin_kernel<<<64, THREADS, 0, stream>>>(pmin, facc, (float*)d_out,
                                                        totalQ, 1.0f / (B * N));
    } else {
        unsigned int* minsq = (unsigned int*)d_ws;
        hipMemsetAsync(minsq, 0x7F, (size_t)totalQ * sizeof(unsigned int), stream);
        int nQC = N / 1024, nTC = N / 256;
        int blocksPerDir = B * nQC * nTC;
        nn_fallback_kernel<<<2 * blocksPerDir, THREADS, 0, stream>>>(
            pred, gt, minsq, N, B, nQC, nTC, blocksPerDir);
        reduce1_direct_kernel<<<64, THREADS, 0, stream>>>(minsq, partials, totalQ);
        reduce2_kernel<<<1, 64, 0, stream>>>(partials, (float*)d_out, 1.0f / (B * N));
    }
}

// Round 19
// 29.085 us; speedup vs baseline: 1.5245x; 1.5245x over previous
//
#include <hip/hip_runtime.h>

#define THREADS 256
#define NB 4                 // batches
#define NPTS 8192            // points per cloud
#define CHT 32               // A-tiles per LDS chunk (32 KB)
#define NCH 8                // target chunks per (dir,b)

typedef __attribute__((ext_vector_type(8))) short short8;   // 8 bf16 = 4 VGPR
typedef __attribute__((ext_vector_type(16))) float f32x16;  // MFMA 32x32 acc

__device__ inline unsigned short f2b(float f) {  // f32 -> bf16 RNE (no NaN inputs here)
    unsigned u = __float_as_uint(f);
    return (unsigned short)((u + 0x7FFFu + ((u >> 16) & 1u)) >> 16);
}
__device__ inline float b2f(unsigned short h) {
    return __uint_as_float(((unsigned)h) << 16);
}

// Fragment K-slot plan (verified absmax=0 rounds 7-18):
// A (targets, rows; lane row=l&31, kgrp=l>>5):
//   kgrp0: [ghx ghy ghz glx gly glz ghx ghy]  kgrp1: [ghz g2h g2l 0 0 0 0 0]
// B (queries, cols; a=split(-2p)):
//   kgrp0: [ahx ahy ahz ahx ahy ahz alx aly]  kgrp1: [alz 1 1 0 0 0 0 0]
// => acc[target][query] = |g|^2 - 2 p.g  (+|p|^2 in epilogue)

// Empirical best (r13): VGPR-dest MFMA pair + 18 wait-states before any
// external VALU read of the results (hazard recognizer can't see into asm).
#define MFMA_PAIR(c0, c1, a0, a1, bq, z)                                   \
    asm("v_mfma_f32_32x32x16_bf16 %0, %2, %4, %5\n\t"                      \
        "v_mfma_f32_32x32x16_bf16 %1, %3, %4, %5\n\t"                      \
        "s_nop 7\n\t"                                                      \
        "s_nop 7\n\t"                                                      \
        "s_nop 1"                                                          \
        : "=&v"(c0), "=&v"(c1)                                             \
        : "v"(a0), "v"(a1), "v"(bq), "v"(z))

// Fused: stage A-chunk fragments in LDS from raw coords; B-frags in registers.
// block = (dir, b, chunk, qpg); 4 waves each own one query pair vs the chunk.
// No atomics: per-(query,chunk) partial min stored to pmin[gi*8+chunk].
__global__ __launch_bounds__(THREADS, 4) void nn_fused_kernel(
    const float* __restrict__ pred, const float* __restrict__ gt,
    float* __restrict__ pmin, int N)
{
    __shared__ short8 lA[CHT * 64];   // 32 KB

    int wave = threadIdx.x >> 6;
    int lane = threadIdx.x & 63;
    int blk = blockIdx.x;             // [0, 2048)
    int dir   = blk >> 10;
    int b     = (blk >> 8) & 3;
    int chunk = (blk >> 5) & 7;       // 8 chunks of 32 tiles (1024 targets)
    int qpg   = blk & 31;             // 32 query-pair groups (x4 waves)

    const float* q = (dir ? gt : pred) + (size_t)b * 3 * N;  // queries
    const float* t = (dir ? pred : gt) + (size_t)b * 3 * N;  // targets

    // ---- stage A-chunk: 1024 targets, 4 per thread, coalesced in jj ----
    int cbase = chunk * (CHT * 32);
    #pragma unroll
    for (int k = 0; k < 4; ++k) {
        int jj = k * THREADS + threadIdx.x;      // [0,1024)
        int j  = cbase + jj;
        float gx = t[j], gy = t[N + j], gz = t[2 * N + j];
        unsigned short ghx = f2b(gx), ghy = f2b(gy), ghz = f2b(gz);
        unsigned short glx = f2b(gx - b2f(ghx)), gly = f2b(gy - b2f(ghy)), glz = f2b(gz - b2f(ghz));
        float g2 = fmaf(gx, gx, fmaf(gy, gy, gz * gz));
        unsigned short g2h = f2b(g2), g2l = f2b(g2 - b2f(g2h));
        short8 ta0, ta1;
        ta0[0]=(short)ghx; ta0[1]=(short)ghy; ta0[2]=(short)ghz; ta0[3]=(short)glx;
        ta0[4]=(short)gly; ta0[5]=(short)glz; ta0[6]=(short)ghx; ta0[7]=(short)ghy;
        ta1[0]=(short)ghz; ta1[1]=(short)g2h; ta1[2]=(short)g2l; ta1[3]=0;
        ta1[4]=0; ta1[5]=0; ta1[6]=0; ta1[7]=0;
        int tile = jj >> 5, c = jj & 31;
        lA[tile * 64 + c]      = ta0;
        lA[tile * 64 + 32 + c] = ta1;
    }

    // ---- build this wave's B-fragments (2 query tiles) + |p|^2 ----
    int qp = qpg * 4 + wave;                 // query pair [0,128)
    int hi = lane >> 5;
    int qj0 = qp * 64 + (lane & 31);         // tile 2qp,   col lane&31
    int qj1 = qj0 + 32;                      // tile 2qp+1, col lane&31
    const short ONE = (short)0x3F80;

    short8 bq0, bq1;
    float p20, p21;
    {
        float px = q[qj0], py = q[N + qj0], pz = q[2 * N + qj0];
        p20 = fmaf(px, px, fmaf(py, py, pz * pz));
        float ax = -2.f * px, ay = -2.f * py, az = -2.f * pz;
        unsigned short ahx = f2b(ax), ahy = f2b(ay), ahz = f2b(az);
        unsigned short alx = f2b(ax - b2f(ahx)), aly = f2b(ay - b2f(ahy)), alz = f2b(az - b2f(ahz));
        short8 v0, v1;
        v0[0]=(short)ahx; v0[1]=(short)ahy; v0[2]=(short)ahz; v0[3]=(short)ahx;
        v0[4]=(short)ahy; v0[5]=(short)ahz; v0[6]=(short)alx; v0[7]=(short)aly;
        v1[0]=(short)alz; v1[1]=ONE; v1[2]=ONE; v1[3]=0; v1[4]=0; v1[5]=0; v1[6]=0; v1[7]=0;
        bq0 = hi ? v1 : v0;
    }
    {
        float px = q[qj1], py = q[N + qj1], pz = q[2 * N + qj1];
        p21 = fmaf(px, px, fmaf(py, py, pz * pz));
        float ax = -2.f * px, ay = -2.f * py, az = -2.f * pz;
        unsigned short ahx = f2b(ax), ahy = f2b(ay), ahz = f2b(az);
        unsigned short alx = f2b(ax - b2f(ahx)), aly = f2b(ay - b2f(ahy)), alz = f2b(az - b2f(ahz));
        short8 v0, v1;
        v0[0]=(short)ahx; v0[1]=(short)ahy; v0[2]=(short)ahz; v0[3]=(short)ahx;
        v0[4]=(short)ahy; v0[5]=(short)ahz; v0[6]=(short)alx; v0[7]=(short)aly;
        v1[0]=(short)alz; v1[1]=ONE; v1[2]=ONE; v1[3]=0; v1[4]=0; v1[5]=0; v1[6]=0; v1[7]=0;
        bq1 = hi ? v1 : v0;
    }

    f32x16 z;
    #pragma unroll
    for (int i = 0; i < 16; ++i) z[i] = 0.f;

    f32x16 vm0, vm1;
    #pragma unroll
    for (int i = 0; i < 16; ++i) { vm0[i] = 3.0e38f; vm1[i] = 3.0e38f; }

    __syncthreads();

    // ---- main loop ----
    for (int tt = 0; tt < CHT; tt += 2) {
        short8 a0 = lA[tt * 64 + lane];
        short8 a1 = lA[tt * 64 + 64 + lane];
        {
            f32x16 c0, c1;
            MFMA_PAIR(c0, c1, a0, a1, bq0, z);
            #pragma unroll
            for (int i = 0; i < 16; ++i) vm0[i] = fminf(vm0[i], fminf(c0[i], c1[i]));
        }
        {
            f32x16 c0, c1;
            MFMA_PAIR(c0, c1, a0, a1, bq1, z);
            #pragma unroll
            for (int i = 0; i < 16; ++i) vm1[i] = fminf(vm1[i], fminf(c0[i], c1[i]));
        }
    }

    // ---- epilogue: horizontal min (tree) + xor-32 merge + partial store ----
    int qbase = (dir * NB + b) * N + qp * 64;
    #pragma unroll
    for (int qi = 0; qi < 2; ++qi) {
        f32x16 vv = qi == 0 ? vm0 : vm1;
        float p2 = qi == 0 ? p20 : p21;
        float m0 = fminf(fminf(vv[0], vv[1]), fminf(vv[2], vv[3]));
        float m1 = fminf(fminf(vv[4], vv[5]), fminf(vv[6], vv[7]));
        float m2 = fminf(fminf(vv[8], vv[9]), fminf(vv[10], vv[11]));
        float m3 = fminf(fminf(vv[12], vv[13]), fminf(vv[14], vv[15]));
        float v = fminf(fminf(m0, m1), fminf(m2, m3));
        v = fminf(v, __shfl_xor(v, 32));
        if (lane < 32) {
            pmin[(size_t)(qbase + qi * 32 + lane) * NCH + chunk] = fmaxf(v + p2, 0.f);
        }
    }
}

// reduce1 (main path): 8-way chunk min + sqrt + per-block sum
__global__ __launch_bounds__(THREADS) void reduce1_pmin_kernel(
    const float* __restrict__ pmin, float* __restrict__ partials, int totalQ)
{
    __shared__ float sdata[THREADS];
    float s = 0.f;
    for (int gi = blockIdx.x * THREADS + threadIdx.x; gi < totalQ; gi += gridDim.x * THREADS) {
        const float4* p = (const float4*)(pmin + (size_t)gi * NCH);
        float4 u = p[0], w = p[1];
        float m = fminf(fminf(fminf(u.x, u.y), fminf(u.z, u.w)),
                        fminf(fminf(w.x, w.y), fminf(w.z, w.w)));
        s += sqrtf(m + 1e-8f);
    }
    sdata[threadIdx.x] = s;
    __syncthreads();
    for (int off = THREADS / 2; off > 0; off >>= 1) {
        if (threadIdx.x < off) sdata[threadIdx.x] += sdata[threadIdx.x + off];
        __syncthreads();
    }
    if (threadIdx.x == 0) partials[blockIdx.x] = sdata[0];
}

// Fallback (unexpected shape): direct f32 path + atomicMin on uint bits.
__global__ __launch_bounds__(THREADS) void nn_fallback_kernel(
    const float* __restrict__ pred, const float* __restrict__ gt,
    unsigned int* __restrict__ minsq, int N, int B, int nQC, int nTC, int blocksPerDir)
{
    int blk = blockIdx.x;
    int dir = blk / blocksPerDir;
    blk -= dir * blocksPerDir;
    int tc = blk % nTC;
    int qc = (blk / nTC) % nQC;
    int b  = blk / (nTC * nQC);
    const float* q = (dir ? gt : pred) + (size_t)b * 3 * N;
    const float* t = (dir ? pred : gt) + (size_t)b * 3 * N + tc * 256;
    float px[4], py[4], pz[4], p2[4], mn[4];
    int q0 = qc * 1024 + threadIdx.x;
    #pragma unroll
    for (int r = 0; r < 4; ++r) {
        int qi = q0 + r * THREADS;
        px[r] = -2.f * q[qi]; py[r] = -2.f * q[N + qi]; pz[r] = -2.f * q[2 * N + qi];
        p2[r] = fmaf(q[qi], q[qi], fmaf(q[N + qi], q[N + qi], q[2 * N + qi] * q[2 * N + qi]));
        mn[r] = 3.0e38f;
    }
    for (int j = 0; j < 256; j += 4) {
        float4 gx4 = *(const float4*)&t[j];
        float4 gy4 = *(const float4*)&t[N + j];
        float4 gz4 = *(const float4*)&t[2 * N + j];
        float g2_0 = fmaf(gx4.x, gx4.x, fmaf(gy4.x, gy4.x, gz4.x * gz4.x));
        float g2_1 = fmaf(gx4.y, gx4.y, fmaf(gy4.y, gy4.y, gz4.y * gz4.y));
        float g2_2 = fmaf(gx4.z, gx4.z, fmaf(gy4.z, gy4.z, gz4.z * gz4.z));
        float g2_3 = fmaf(gx4.w, gx4.w, fmaf(gy4.w, gy4.w, gz4.w * gz4.w));
        #pragma unroll
        for (int r = 0; r < 4; ++r) {
            float d0 = fmaf(gx4.x, px[r], fmaf(gy4.x, py[r], fmaf(gz4.x, pz[r], g2_0)));
            float d1 = fmaf(gx4.y, px[r], fmaf(gy4.y, py[r], fmaf(gz4.y, pz[r], g2_1)));
            float d2 = fmaf(gx4.z, px[r], fmaf(gy4.z, py[r], fmaf(gz4.z, pz[r], g2_2)));
            float d3 = fmaf(gx4.w, px[r], fmaf(gy4.w, py[r], fmaf(gz4.w, pz[r], g2_3)));
            mn[r] = fminf(fminf(d0, d1), mn[r]);
            mn[r] = fminf(fminf(d2, d3), mn[r]);
        }
    }
    unsigned int* mb = minsq + ((size_t)dir * B + b) * N;
    #pragma unroll
    for (int r = 0; r < 4; ++r) {
        float d2 = fmaxf(mn[r] + p2[r], 0.f);
        atomicMin(&mb[q0 + r * THREADS], __float_as_uint(d2));
    }
}

__global__ __launch_bounds__(THREADS) void reduce1_direct_kernel(
    const unsigned int* __restrict__ minsq, float* __restrict__ partials, int total)
{
    __shared__ float sdata[THREADS];
    float s = 0.f;
    for (int i = blockIdx.x * THREADS + threadIdx.x; i < total; i += gridDim.x * THREADS) {
        float v = __uint_as_float(minsq[i]);
        s += sqrtf(v + 1e-8f);
    }
    sdata[threadIdx.x] = s;
    __syncthreads();
    for (int off = THREADS / 2; off > 0; off >>= 1) {
        if (threadIdx.x < off) sdata[threadIdx.x] += sdata[threadIdx.x + off];
        __syncthreads();
    }
    if (threadIdx.x == 0) partials[blockIdx.x] = sdata[0];
}

__global__ __launch_bounds__(64) void reduce2_kernel(
    const float* __restrict__ partials, float* __restrict__ out, float inv)
{
    float s = partials[threadIdx.x];
    #pragma unroll
    for (int off = 32; off > 0; off >>= 1) s += __shfl_down(s, off);
    if (threadIdx.x == 0) out[0] = s * inv;
}

extern "C" void kernel_launch(void* const* d_in, const int* in_sizes, int n_in,
                              void* d_out, int out_size, void* d_ws, size_t ws_size,
                              hipStream_t stream) {
    const float* pred = (const float*)d_in[0];
    const float* gt   = (const float*)d_in[1];
    const int N = 8192;
    const int B = in_sizes[0] / (3 * N);
    int totalQ = 2 * B * N;                               // 65536

    float* pmin     = (float*)d_ws;                       // 2*B*N*8 floats = 2 MB
    float* partials = (float*)((char*)d_ws + (4 << 20));  // 64 floats

    if (B == NB && N == NPTS) {
        nn_fused_kernel<<<2048, THREADS, 0, stream>>>(pred, gt, pmin, N);
        reduce1_pmin_kernel<<<64, THREADS, 0, stream>>>(pmin, partials, totalQ);
    } else {
        unsigned int* minsq = (unsigned int*)d_ws;
        hipMemsetAsync(minsq, 0x7F, (size_t)totalQ * sizeof(unsigned int), stream);
        int nQC = N / 1024, nTC = N / 256;
        int blocksPerDir = B * nQC * nTC;
        nn_fallback_kernel<<<2 * blocksPerDir, THREADS, 0, stream>>>(
            pred, gt, minsq, N, B, nQC, nTC, blocksPerDir);
        reduce1_direct_kernel<<<64, THREADS, 0, stream>>>(minsq, partials, totalQ);
    }

    reduce2_kernel<<<1, 64, 0, stream>>>(partials, (float*)d_out, 1.0f / (B * N));
}